// Round 1
// 111.882 us; speedup vs baseline: 1.0083x; 1.0083x over previous
//
#include <hip/hip_runtime.h>
#include <math.h>

#define B_   8
#define CIN  256
#define L_   1024
#define NH_  8
#define DH_  32

typedef __attribute__((ext_vector_type(8))) short short8;
typedef __attribute__((ext_vector_type(4))) short short4v;
typedef __attribute__((ext_vector_type(4))) float f32x4;
typedef __attribute__((ext_vector_type(4))) unsigned int uint4v;
typedef __attribute__((ext_vector_type(2))) unsigned int uint2v;

__device__ inline short f2bf_hu(float f) {       // bf16 half-up, 2 ops
    union { float f; unsigned u; } v; v.f = f;
    return (short)((v.u + 0x8000u) >> 16);
}
__device__ inline float bf2f(short s) {          // bf16 -> fp32, 1 shift
    union { unsigned u; float f; } v; v.u = ((unsigned)(unsigned short)s) << 16;
    return v.f;
}
// pack bf16(a) | bf16(b)<<16 : 2 adds + 1 v_perm
__device__ inline unsigned pkbf2(float a, float b) {
    union { float f; unsigned u; } x, y; x.f = a; y.f = b;
    return __builtin_amdgcn_perm(y.u + 0x8000u, x.u + 0x8000u, 0x07060302u);
}
// async global->LDS, 16B per lane; LDS dest = wave-uniform base + lane*16
__device__ inline void glds16(const void* g, void* l) {
    __builtin_amdgcn_global_load_lds(
        (const __attribute__((address_space(1))) void*)g,
        (__attribute__((address_space(3))) void*)l, 16, 0, 0);
}

// ---------------------------------------------------------------------------
// Weight pre-convert: w_qkv (768x256) and w_proj (256x256) fp32 -> bf16,
// plain [o][c] rows. Rounding = pkbf2 half-up, identical to previous inline
// conversion, so results stay bit-exact. 128 blocks x 256 thr, 8 elems/thr.
// ---------------------------------------------------------------------------
__global__ __launch_bounds__(256) void wconv(
    const float* __restrict__ wq, const float* __restrict__ wp,
    short* __restrict__ w2)
{
    const size_t e = ((size_t)blockIdx.x * 256 + threadIdx.x) * 8;
    const float* src = (e < (size_t)768 * 256) ? wq + e : wp + (e - (size_t)768 * 256);
    const float4 a = *(const float4*)src;
    const float4 c = *(const float4*)(src + 4);
    uint4v pk = { pkbf2(a.x, a.y), pkbf2(a.z, a.w),
                  pkbf2(c.x, c.y), pkbf2(c.z, c.w) };
    *(uint4v*)(w2 + e) = pk;
}

// ---------------------------------------------------------------------------
// QKV GEMM, restructured: single barrier per K-step, double-buffered LDS,
// W staged via global_load_lds (bf16, swizzle pre-applied to global source),
// X tile register-prefetched one step ahead. Same tile 64(l) x 128(o),
// grid 16x6x8 = 768 blocks = 3/CU (LDS 26.6 KB -> still 3 blocks/CU).
// ---------------------------------------------------------------------------
__global__ __launch_bounds__(256) void qkv_gemm(
    const float* __restrict__ x, const short* __restrict__ w2,
    const float* __restrict__ bias, short* __restrict__ qkvT)
{
    __shared__ __align__(16) short Xs[2][64][40];
    __shared__ __align__(16) short Wt[2][128][32];   // linear rows, swizzled content
    const int t = threadIdx.x, lane = t & 63, wv = t >> 6;
    const int n = lane & 15, quad = lane >> 4;
    const int b = blockIdx.z, o0 = blockIdx.y * 128, l0 = blockIdx.x * 64;

    float bias_r[8];
    #pragma unroll
    for (int nf = 0; nf < 8; nf++) bias_r[nf] = bias[o0 + nf * 16 + n];

    f32x4 acc[8];
    #pragma unroll
    for (int nf = 0; nf < 8; nf++) acc[nf] = (f32x4){0.f, 0.f, 0.f, 0.f};

    const int cS = t >> 3, lsS = (t & 7) * 8;       // X stage roles

    // W glds: wave covers rows [wv*32, wv*32+32) via two 1KB issues.
    // LDS chunk i (16B) holds c-chunk (i&3)^((o>>1)&3) of row o -> fragment
    // reads at slot quad^((row>>1)&3) are 2-way bank aliased (free).
    const int oA = wv * 32 + (lane >> 2);
    const int cc = (lane & 3) ^ ((oA >> 1) & 3);    // same for oA+16
    const short* wpA = w2 + (size_t)(o0 + oA) * 256 + cc * 8;
    const short* wpB = wpA + 16 * 256;
    short* const ldsW0 = &Wt[0][0][0] + wv * 1024;
    short* const ldsW1 = &Wt[1][0][0] + wv * 1024;

    auto xwrite = [&](int buf, const float4& a, const float4& c) {
        const float vals[8] = {a.x, a.y, a.z, a.w, c.x, c.y, c.z, c.w};
        #pragma unroll
        for (int k = 0; k < 8; k++) {
            const int ll = lsS + k;
            const int col = (((cS >> 3) ^ (ll & 3)) << 3) | (cS & 7);
            Xs[buf][ll][col] = f2bf_hu(vals[k]);
        }
    };

    // prologue: W(0) async, X(0) -> Xs[0], prefetch X(1)
    const float* xp = &x[(((size_t)b * CIN + cS) << 10) + l0 + lsS];
    float4 xa = *(const float4*)xp, xb = *(const float4*)(xp + 4);
    glds16(wpA, ldsW0);
    glds16(wpB, ldsW0 + 512);
    xwrite(0, xa, xb);
    xp += (size_t)32 << 10;
    xa = *(const float4*)xp; xb = *(const float4*)(xp + 4);

    const int wsw = (quad ^ ((n >> 1) & 3)) * 8;
    const int arow = wv * 16 + n;
    const int xsw = (quad ^ (arow & 3)) * 8;

    #pragma unroll
    for (int it = 0; it < 8; it++) {
        const int cur = it & 1;
        __syncthreads();                            // buf[cur] ready (vmcnt+lgkm drain)
        if (it < 7) {                               // W(it+1) into idle buffer
            short* ldsn = (cur ? ldsW0 : ldsW1);
            glds16(wpA + (it + 1) * 32, ldsn);
            glds16(wpB + (it + 1) * 32, ldsn + 512);
        }
        const short8 af = *(const short8*)&Xs[cur][arow][xsw];
        #pragma unroll
        for (int nf = 0; nf < 8; nf++) {
            const short8 bf = *(const short8*)&Wt[cur][nf * 16 + n][wsw];
            acc[nf] = __builtin_amdgcn_mfma_f32_16x16x32_bf16(af, bf, acc[nf], 0, 0, 0);
        }
        if (it < 7) {                               // X(it+1) into idle buffer
            xwrite(cur ^ 1, xa, xb);
            if (it < 6) {                           // prefetch X(it+2)
                xp += (size_t)32 << 10;
                xa = *(const float4*)xp; xb = *(const float4*)(xp + 4);
            }
        }
    }

    #pragma unroll
    for (int reg = 0; reg < 4; reg++) {
        const size_t l = l0 + wv * 16 + quad * 4 + reg;
        short* row = qkvT + (((size_t)b << 10) + l) * 768 + o0 + n;
        #pragma unroll
        for (int nf = 0; nf < 8; nf++)
            row[nf * 16] = f2bf_hu(acc[nf][reg] + bias_r[nf]);
    }
}

// ---------------------------------------------------------------------------
// Proj GEMM, same restructure: single barrier / K-step, double-buffered LDS,
// W via global_load_lds (pre-converted bf16), partial-combine operands
// register-prefetched one step ahead. Output math unchanged.
// ---------------------------------------------------------------------------
__global__ __launch_bounds__(256) void proj_gemm(
    const short* __restrict__ partO, const float* __restrict__ partD,
    const short* __restrict__ w2, const float* __restrict__ bias,
    const float* __restrict__ resid, float* __restrict__ out)
{
    __shared__ __align__(16) short Xs[2][64][40];
    __shared__ __align__(16) short Wt[2][64][32];
    const int t = threadIdx.x, lane = t & 63, wv = t >> 6;
    const int n = lane & 15, quad = lane >> 4;
    const int b = blockIdx.z, o0 = blockIdx.y * 64, l0 = blockIdx.x * 64;

    float bias_r[4];
    #pragma unroll
    for (int reg = 0; reg < 4; reg++) bias_r[reg] = bias[o0 + wv * 16 + quad * 4 + reg];

    f32x4 acc[4];
    #pragma unroll
    for (int nf = 0; nf < 4; nf++) acc[nf] = (f32x4){0.f, 0.f, 0.f, 0.f};

    // combine-stage roles: one l-row, 8 c's per thread
    const int l = t >> 2, cs = (t & 3) * 8;
    const size_t li = ((size_t)b << 10) + l0 + l;
    const short* p0 = &partO[(0 * (size_t)B_ * L_ + li) * CIN + cs];
    const short* p1 = &partO[(1 * (size_t)B_ * L_ + li) * CIN + cs];
    const float* pd0 = &partD[(0 * (size_t)B_ * L_ + li) * NH_];
    const float* pd1 = &partD[(1 * (size_t)B_ * L_ + li) * NH_];

    // W glds: 64 rows x 64B per buffer, one 1KB issue per wave
    const int og = wv * 16 + (lane >> 2);
    const int ccg = (lane & 3) ^ ((og >> 1) & 3);
    const short* wp = w2 + (size_t)(o0 + og) * 256 + ccg * 8;
    short* const ldsW0 = &Wt[0][0][0] + wv * 512;
    short* const ldsW1 = &Wt[1][0][0] + wv * 512;

    short8 s0, s1;
    float d0, d1;
    auto combine_write = [&](int buf) {
        const float inv = 1.f / (d0 + d1);
        float v[8];
        #pragma unroll
        for (int e = 0; e < 8; e++) v[e] = (bf2f(s0[e]) + bf2f(s1[e])) * inv;
        uint4v pw = { pkbf2(v[0], v[1]), pkbf2(v[2], v[3]),
                      pkbf2(v[4], v[5]), pkbf2(v[6], v[7]) };
        *(uint4v*)&Xs[buf][l][cs] = pw;
    };

    // prologue
    s0 = *(const short8*)p0; s1 = *(const short8*)p1;
    d0 = pd0[0]; d1 = pd1[0];
    glds16(wp, ldsW0);
    combine_write(0);
    p0 += 32; p1 += 32;
    s0 = *(const short8*)p0; s1 = *(const short8*)p1;
    d0 = pd0[1]; d1 = pd1[1];

    const int wsw = (quad ^ ((n >> 1) & 3)) * 8;
    #pragma unroll
    for (int it = 0; it < 8; it++) {
        const int cur = it & 1;
        __syncthreads();
        if (it < 7) glds16(wp + (it + 1) * 32, cur ? ldsW0 : ldsW1);
        const short8 af = *(const short8*)&Wt[cur][wv * 16 + n][wsw];
        #pragma unroll
        for (int nf = 0; nf < 4; nf++) {
            const short8 bf = *(const short8*)&Xs[cur][nf * 16 + n][quad * 8];
            acc[nf] = __builtin_amdgcn_mfma_f32_16x16x32_bf16(af, bf, acc[nf], 0, 0, 0);
        }
        if (it < 7) {
            combine_write(cur ^ 1);
            if (it < 6) {
                p0 += 32; p1 += 32;
                s0 = *(const short8*)p0; s1 = *(const short8*)p1;
                d0 = pd0[it + 2]; d1 = pd1[it + 2];
            }
        }
    }

    #pragma unroll
    for (int reg = 0; reg < 4; reg++) {
        const int o = o0 + wv * 16 + quad * 4 + reg;
        #pragma unroll
        for (int nf = 0; nf < 4; nf++) {
            const size_t off = (((size_t)b * CIN + o) << 10) + l0 + nf * 16 + n;
            out[off] = acc[nf][reg] + bias_r[reg] + resid[off];
        }
    }
}

// ---------------------------------------------------------------------------
// Flash attention (unchanged from the 112.8us baseline): Q-tile 128, 2
// m-frags/wave, K direct, V LDS double-buffered, register ones-column,
// exp2 intrinsic, bumped pointers, Ss stride 88, XCD swizzle, split-j x2.
// ---------------------------------------------------------------------------
__global__ __launch_bounds__(256) void attn_mfma(
    const short* __restrict__ qkvT, short* __restrict__ partO,
    float* __restrict__ partD)
{
    __shared__ short Vt[2][32][80];                // col ^= ((dv>>2)&7)<<3
    __shared__ __align__(16) short Ss[128][88];    // [i][j] bf16 P (wave-private rows)

    const int t = threadIdx.x, lane = t & 63, wv = t >> 6;
    const int n = lane & 15, quad = lane >> 4;
    const int id = blockIdx.x;
    const int bh = id & 63;                        // same-(b,h) -> same XCD
    const int b = bh >> 3, h = bh & 7;
    const int i0 = ((id >> 6) & 7) * 128;
    const int s  = id >> 9;                        // j-split 0/1

    const short* base = qkvT + ((size_t)b << 10) * 768;

    short8 qa[2];
    #pragma unroll
    for (int a = 0; a < 2; a++)
        qa[a] = *(const short8*)&base[(size_t)(i0 + wv * 32 + a * 16 + n) * 768
                                      + h * DH_ + quad * 8];

    short8 vf2;   // ones-column B-frag (denominator)
    {
        const short one = (n == 0) ? (short)0x3F80 : (short)0;
        #pragma unroll
        for (int u = 0; u < 8; u++) vf2[u] = one;
    }

    f32x4 o_acc[2][3];
    #pragma unroll
    for (int a = 0; a < 2; a++)
        #pragma unroll
        for (int nf = 0; nf < 3; nf++) o_acc[a][nf] = (f32x4){0.f, 0.f, 0.f, 0.f};

    const float K1 = 0.25503510f;    // (1/sqrt(32)) * log2(e)
    const float K2 = 11.54156036f;   // 8 * log2(e)
    const int TSTRIDE = 64 * 768;    // shorts per j-tile

    const size_t soff = (size_t)s * 8 * TSTRIDE;   // this block's j-half
    const short* kp0 = base + 256 + h * DH_ + (size_t)n * 768 + quad * 8 + soff;
    const short* kp1 = kp0 + 16 * 768;
    const short* kp2 = kp0 + 32 * 768;
    const short* kp3 = kp0 + 48 * 768;
    const int jS = t >> 3, dsS = (t & 7) * 4;
    const short* vp0 = base + 512 + h * DH_ + (size_t)jS * 768 + dsS + soff;
    const short* vp1 = vp0 + 32 * 768;

    const int vmsk = ((dsS >> 2) & 7) << 3;
    const int vwo0 = dsS * 80 + (jS ^ vmsk);
    const int vwo1 = dsS * 80 + ((jS + 32) ^ vmsk);
    short* const vtb0 = &Vt[0][0][0];
    short* const vtb1 = &Vt[1][0][0];
    short* const ssw  = &Ss[wv * 32 + n][quad * 4];        // + a*16*88 + f*16
    const short* const ssr = &Ss[wv * 32 + n][quad * 8];   // + a*16*88 + kk*32
    int vro[2][2];
    #pragma unroll
    for (int nf = 0; nf < 2; nf++) {
        const int dv = nf * 16 + n;
        const int msk = ((dv >> 2) & 7) << 3;
        #pragma unroll
        for (int kk = 0; kk < 2; kk++)
            vro[kk][nf] = dv * 80 + ((kk * 32 + quad * 8) ^ msk);
    }

    short8 kfA[4], kfB[4];

    auto stageV = [&](short* vtb) {
        const short4v a = *(const short4v*)vp0; vp0 += TSTRIDE;
        const short4v c = *(const short4v*)vp1; vp1 += TSTRIDE;
        #pragma unroll
        for (int u = 0; u < 4; u++) {
            vtb[vwo0 + u * 80] = a[u];
            vtb[vwo1 + u * 80] = c[u];
        }
    };
    auto loadK = [&](short8* kf) {
        kf[0] = *(const short8*)kp0; kp0 += TSTRIDE;
        kf[1] = *(const short8*)kp1; kp1 += TSTRIDE;
        kf[2] = *(const short8*)kp2; kp2 += TSTRIDE;
        kf[3] = *(const short8*)kp3; kp3 += TSTRIDE;
    };
    auto tile = [&](const short8* kf, const short* vtb) {
        #pragma unroll
        for (int f = 0; f < 4; f++) {
            #pragma unroll
            for (int a = 0; a < 2; a++) {
                f32x4 z = {0.f, 0.f, 0.f, 0.f};
                const f32x4 sv = __builtin_amdgcn_mfma_f32_16x16x32_bf16(kf[f], qa[a], z, 0, 0, 0);
                const float p0 = __builtin_amdgcn_exp2f(fmaf(sv[0], K1, -K2));
                const float p1 = __builtin_amdgcn_exp2f(fmaf(sv[1], K1, -K2));
                const float p2 = __builtin_amdgcn_exp2f(fmaf(sv[2], K1, -K2));
                const float p3 = __builtin_amdgcn_exp2f(fmaf(sv[3], K1, -K2));
                uint2v pk = { pkbf2(p0, p1), pkbf2(p2, p3) };
                *(uint2v*)(ssw + a * 16 * 88 + f * 16) = pk;
            }
        }
        // wave-private Ss rows: in-wave DS ordering, no barrier
        #pragma unroll
        for (int kk = 0; kk < 2; kk++) {
            short8 pf[2];
            #pragma unroll
            for (int a = 0; a < 2; a++)
                pf[a] = *(const short8*)(ssr + a * 16 * 88 + kk * 32);
            #pragma unroll
            for (int nf = 0; nf < 2; nf++) {
                const short8 vf = *(const short8*)(vtb + vro[kk][nf]);
                #pragma unroll
                for (int a = 0; a < 2; a++)
                    o_acc[a][nf] = __builtin_amdgcn_mfma_f32_16x16x32_bf16(pf[a], vf, o_acc[a][nf], 0, 0, 0);
            }
            #pragma unroll
            for (int a = 0; a < 2; a++)
                o_acc[a][2] = __builtin_amdgcn_mfma_f32_16x16x32_bf16(pf[a], vf2, o_acc[a][2], 0, 0, 0);
        }
    };

    stageV(vtb0);
    loadK(kfA);

    for (int itp = 0; itp < 4; itp++) {     // 8 j-tiles (this block's half)
        __syncthreads();
        stageV(vtb1);
        loadK(kfB);
        tile(kfA, vtb0);
        __syncthreads();
        if (itp < 3) { stageV(vtb0); loadK(kfA); }
        tile(kfB, vtb1);
    }

    // ---- epilogue: bf16 partial stores (half traffic), fp32 denominators ----
    #pragma unroll
    for (int a = 0; a < 2; a++) {
        #pragma unroll
        for (int r = 0; r < 4; r++) {
            const int il = i0 + wv * 32 + a * 16 + quad * 4 + r;
            short* po = partO + (((size_t)s * B_ + b) * L_ + il) * CIN + h * DH_;
            po[n]      = f2bf_hu(o_acc[a][0][r]);
            po[16 + n] = f2bf_hu(o_acc[a][1][r]);
        }
    }
    if (n == 0) {
        #pragma unroll
        for (int a = 0; a < 2; a++)
            #pragma unroll
            for (int r = 0; r < 4; r++) {
                const int il = i0 + wv * 32 + a * 16 + quad * 4 + r;
                partD[(((size_t)s * B_ + b) * L_ + il) * NH_ + h] = o_acc[a][2][r];
            }
    }
}

// ---------------------------------------------------------------------------
extern "C" void kernel_launch(void* const* d_in, const int* in_sizes, int n_in,
                              void* d_out, int out_size, void* d_ws, size_t ws_size,
                              hipStream_t stream) {
    const float* x      = (const float*)d_in[0];
    const float* w_qkv  = (const float*)d_in[1];
    const float* b_qkv  = (const float*)d_in[2];
    const float* w_proj = (const float*)d_in[3];
    const float* b_proj = (const float*)d_in[4];
    float* out = (float*)d_out;

    short* qkvT  = (short*)d_ws;                                // 12 MB bf16 [b][l][768]
    short* partO = qkvT + (size_t)B_ * L_ * 768;                // 8.4 MB bf16 [2][b][l][256]
    float* partD = (float*)(partO + (size_t)2 * B_ * L_ * CIN); // 0.5 MB fp32 [2][b][l][8]
    short* w2    = (short*)(partD + (size_t)2 * B_ * L_ * NH_); // 0.5 MB bf16 weights

    wconv<<<dim3(128), 256, 0, stream>>>(w_qkv, w_proj, w2);
    qkv_gemm<<<dim3(16, 6, B_), 256, 0, stream>>>(x, w2, b_qkv, qkvT);
    attn_mfma<<<dim3(1024), 256, 0, stream>>>(qkvT, partO, partD);
    proj_gemm<<<dim3(16, 4, B_), 256, 0, stream>>>(partO, partD, w2 + (size_t)768 * 256,
                                                   b_proj, x, out);
}